// Round 1
// 454.016 us; speedup vs baseline: 1.0433x; 1.0433x over previous
//
#include <hip/hip_runtime.h>

// AVWGCN: out[b,n,o] = sum_k sum_i xg_k[b,n,i] * w[k,i,o] + bias[o]
//   xg0 = x, xg1 = S@x, xg2 = 2*S@(S@x) - x   (S = softmax(relu(adj@emb), rows))
// Algebra: never form T2; fold "2*" and "-x" into Wcat = [w0-w2 | w1 | 2*w2].
// GEMM: 256x256 8-phase counted-vmcnt template (T3+T4+T5+T1), BK=64, 8 waves,
// 128 KiB LDS double-buffer. LDS stored k-split [ks][256][32] (64B rows) so both
// global_load_lds dst (lane-linear) and ds_read_b128 frags (16r+4q banks, 8 words
// per bank) are conflict-free with NO swizzle. vmcnt never drains to 0 in the
// main loop (phases 4/8: vmcnt(6) = 3 half-tiles in flight).

typedef __bf16 bf16;
typedef __bf16 bf16x8 __attribute__((ext_vector_type(8)));
typedef float f32x4 __attribute__((ext_vector_type(4)));

__device__ __forceinline__ void async_lds16(const void* g, void* l) {
  __builtin_amdgcn_global_load_lds((const __attribute__((address_space(1))) void*)g,
                                   (__attribute__((address_space(3))) void*)l, 16, 0, 0);
}

#define FENCE() asm volatile("" ::: "memory")
#define BAR()                          \
  do {                                 \
    FENCE();                           \
    __builtin_amdgcn_s_barrier();      \
    FENCE();                           \
  } while (0)
#define WAIT_VM(n) asm volatile("s_waitcnt vmcnt(" #n ")" ::: "memory")

// ---- Wcat[o][kk] bf16, kk in [0,192): [w0-w2 | w1 | 2*w2] transposed to o-rows ----
__global__ __launch_bounds__(256) void build_wcat_k(const float* __restrict__ w, bf16* __restrict__ Wc) {
  int idx = blockIdx.x * 256 + threadIdx.x;
  if (idx >= 64 * 192) return;
  int o = idx / 192, kk = idx - o * 192;
  int k = kk >> 6, i = kk & 63;
  float v;
  if (k == 0)      v = w[i * 64 + o] - w[2 * 4096 + i * 64 + o];
  else if (k == 1) v = w[4096 + i * 64 + o];
  else             v = 2.f * w[2 * 4096 + i * 64 + o];
  Wc[idx] = (bf16)v;
}

// ---- S[n][m] = softmax(relu(adj@emb)) rows, stored bf16. 8 rows per block. ----
__global__ __launch_bounds__(256) void supports_k(const float* __restrict__ adj,
                                                  const float* __restrict__ emb,
                                                  bf16* __restrict__ S) {
  __shared__ float sadj[8][16];
  __shared__ float sred[4];
  const int tid = threadIdx.x;
  const int n0 = blockIdx.x * 8;
  if (tid < 128) sadj[tid >> 4][tid & 15] = adj[n0 * 16 + tid];
  __syncthreads();
  for (int r = 0; r < 8; ++r) {
    float vals[16];
    float mx = 0.f;  // relu => max >= 0
    #pragma unroll
    for (int it = 0; it < 16; ++it) {
      const int j = it * 256 + tid;
      float v = 0.f;
      #pragma unroll
      for (int e = 0; e < 16; ++e) v = fmaf(sadj[r][e], emb[e * 4096 + j], v);
      v = fmaxf(v, 0.f);
      vals[it] = v;
      mx = fmaxf(mx, v);
    }
    #pragma unroll
    for (int off = 32; off > 0; off >>= 1) mx = fmaxf(mx, __shfl_xor(mx, off, 64));
    if ((tid & 63) == 0) sred[tid >> 6] = mx;
    __syncthreads();
    mx = fmaxf(fmaxf(sred[0], sred[1]), fmaxf(sred[2], sred[3]));
    float sum = 0.f;
    #pragma unroll
    for (int it = 0; it < 16; ++it) {
      float ev = __expf(vals[it] - mx);
      vals[it] = ev;
      sum += ev;
    }
    #pragma unroll
    for (int off = 32; off > 0; off >>= 1) sum += __shfl_xor(sum, off, 64);
    __syncthreads();  // all reads of sred (max) done before reuse
    if ((tid & 63) == 0) sred[tid >> 6] = sum;
    __syncthreads();
    const float inv = 1.f / (sred[0] + sred[1] + sred[2] + sred[3]);
    bf16* Srow = S + (n0 + r) * 4096;
    #pragma unroll
    for (int it = 0; it < 16; ++it) Srow[it * 256 + tid] = (bf16)(vals[it] * inv);
    __syncthreads();  // sred reused next r
  }
}

// ---- Xt[b*64+c][m] = bf16(x[b][m][c])  (64x64 fp32 tile via LDS) ----
__global__ __launch_bounds__(256) void xpose_x_k(const float* __restrict__ x, bf16* __restrict__ Xt) {
  __shared__ float tile[64][65];
  const int tid = threadIdx.x;
  const int mt = blockIdx.x, b = blockIdx.y;
  const float* src = x + (b * 4096 + mt * 64) * 64;
  #pragma unroll
  for (int it = 0; it < 16; ++it) {
    const int idx = it * 256 + tid;
    tile[idx >> 6][idx & 63] = src[idx];  // idx = m_local*64 + c, coalesced
  }
  __syncthreads();
  #pragma unroll
  for (int it = 0; it < 16; ++it) {
    const int idx = it * 256 + tid;
    const int rr = idx >> 6, cc = idx & 63;  // rr = c (out row), cc = m_local (out col)
    Xt[(b * 64 + rr) * 4096 + mt * 64 + cc] = (bf16)tile[cc][rr];
  }
}

// ---- bf16 4096x4096 transpose: outT[j][i] = in[i][j] ----
__global__ __launch_bounds__(256) void transpose_bf16_k(const bf16* __restrict__ in, bf16* __restrict__ outT) {
  __shared__ bf16 tile[64][65];
  const int tid = threadIdx.x;
  const int ti = blockIdx.x & 63, tj = blockIdx.x >> 6;
  #pragma unroll
  for (int it = 0; it < 16; ++it) {
    const int idx = it * 256 + tid;
    tile[idx >> 6][idx & 63] = in[(ti * 64 + (idx >> 6)) * 4096 + tj * 64 + (idx & 63)];
  }
  __syncthreads();
  #pragma unroll
  for (int it = 0; it < 16; ++it) {
    const int idx = it * 256 + tid;
    const int rr = idx >> 6, cc = idx & 63;
    outT[(tj * 64 + rr) * 4096 + ti * 64 + cc] = tile[cc][rr];
  }
}

// ---- C[n][bc] = A[n][:] . Bt[bc][:]  (4096^3, both operands K-contig row-major) ----
// 256x256 tile, BK=64, 512 threads = 8 waves (2M x 4N), per-wave 128x64 output,
// acc[8][4] f32x4. 8-phase schedule over 2 K-tiles (buf0 = even tile, buf1 = odd):
//   ph p: { ds_read frags for p+1 | stage 1 half-tile (2 x global_load_lds 16B) |
//           s_barrier | setprio(1) 16xMFMA setprio(0) | s_barrier }
// vmcnt(6) only at ph4/ph8 (3 half-tiles = 6 loads stay in flight). Stage order
// per iter: ph1 t1.Aks1 | ph2 t2.Bks0 | ph3 t2.Aks0 | ph4 t2.Bks1 | ph5 t2.Aks1 |
// ph6 t3.Bks0 | ph7 t3.Aks0 | ph8 t3.Bks1 — each region's reads are issued >=2
// phases before its re-stage, and ph4/ph8 read the fresh buffer AFTER the
// post-vmcnt barrier (cross-wave landing guarantee).
__global__ __launch_bounds__(512, 2) void gemm256_k(const bf16* __restrict__ A,
                                                    const bf16* __restrict__ Bt,
                                                    bf16* __restrict__ C) {
  __shared__ bf16 As[2][2][256][32];  // [buf][ks][row][k'] : 64 KiB
  __shared__ bf16 Bs[2][2][256][32];  // 64 KiB

  const int tid = threadIdx.x;
  const int bid = blockIdx.x;
  const int wg = (bid & 7) * 32 + (bid >> 3);  // XCD swizzle, 256 % 8 == 0 -> bijective
  const int tm = wg >> 4, tn = wg & 15;
  const int rowBase = tm * 256, colBase = tn * 256;

  const int wv = tid >> 6, lane = tid & 63;
  const int wm = wv >> 2, wn = wv & 3;
  const int t16 = lane & 15, quad = lane >> 4;
  const int wv16 = wv * 16;
  const int q8 = quad * 8;
  const int wm128 = wm * 128;
  const int wn64 = wn * 64;

  // staging: thread t -> row t>>2 (128 rows/load), 8-elem chunk t&3 within 32-k half
  const int sr = tid >> 2, sc = (tid & 3) * 8;
  const bf16* gA = A + (size_t)(rowBase + sr) * 4096 + sc;
  const bf16* gB = Bt + (size_t)(colBase + sr) * 4096 + sc;

  f32x4 acc[8][4];
  #pragma unroll
  for (int i = 0; i < 8; ++i)
    #pragma unroll
    for (int j = 0; j < 4; ++j) acc[i][j] = (f32x4){0.f, 0.f, 0.f, 0.f};

  auto stA = [&](int buf, int s, int k0) {
    async_lds16(gA + k0 + s * 32, &As[buf][s][wv16][0]);
    async_lds16(gA + 524288 + k0 + s * 32, &As[buf][s][128 + wv16][0]);
  };
  auto stB = [&](int buf, int s, int k0) {
    async_lds16(gB + k0 + s * 32, &Bs[buf][s][wv16][0]);
    async_lds16(gB + 524288 + k0 + s * 32, &Bs[buf][s][128 + wv16][0]);
  };

  bf16x8 Ra[4], Rb[4], B0[4], B1[4];
  auto rdA = [&](bf16x8* R, int buf, int s, int g) {
    #pragma unroll
    for (int i = 0; i < 4; ++i)
      R[i] = *(const bf16x8*)&As[buf][s][wm128 + (g * 4 + i) * 16 + t16][q8];
  };
  auto rdB = [&](bf16x8* R, int buf, int s) {
    #pragma unroll
    for (int j = 0; j < 4; ++j)
      R[j] = *(const bf16x8*)&Bs[buf][s][wn64 + j * 16 + t16][q8];
  };
  auto mfma16 = [&](int g, const bf16x8* R, const bf16x8* Bv) {
    __builtin_amdgcn_s_setprio(1);
    #pragma unroll
    for (int i = 0; i < 4; ++i)
      #pragma unroll
      for (int j = 0; j < 4; ++j)
        acc[g * 4 + i][j] =
            __builtin_amdgcn_mfma_f32_16x16x32_bf16(R[i], Bv[j], acc[g * 4 + i][j], 0, 0, 0);
    __builtin_amdgcn_s_setprio(0);
  };

  // prologue: t0 -> buf0 (4 halves, 8 loads), t1 -> buf1 (3 halves, 6 loads)
  stB(0, 0, 0); stA(0, 0, 0); stB(0, 1, 0); stA(0, 1, 0);
  stB(1, 0, 64); stA(1, 0, 64); stB(1, 1, 64);
  WAIT_VM(6);  // t0 fully landed; t1's 3 halves may remain in flight
  BAR();
  rdA(Ra, 0, 0, 0);
  rdB(B0, 0, 0);

  for (int it = 0; it < 31; ++it) {
    const int kb = it * 128;
    // ph1: compute t0 (m0-3, ks0)
    rdA(Rb, 0, 0, 1); stA(1, 1, kb + 64);
    BAR(); mfma16(0, Ra, B0); BAR();
    // ph2: (m4-7, ks0)
    rdA(Ra, 0, 1, 0); rdB(B1, 0, 1); stB(0, 0, kb + 128);
    BAR(); mfma16(1, Rb, B0); BAR();
    // ph3: (m0-3, ks1)
    rdA(Rb, 0, 1, 1); stA(0, 0, kb + 128);
    BAR(); mfma16(0, Ra, B1); BAR();
    // ph4: (m4-7, ks1); counted wait -> t1 complete; read buf1 AFTER barrier
    stB(0, 1, kb + 128); WAIT_VM(6);
    BAR();
    rdA(Ra, 1, 0, 0); rdB(B0, 1, 0);
    mfma16(1, Rb, B1); BAR();
    // ph5: compute t1 (m0-3, ks0)
    rdA(Rb, 1, 0, 1); stA(0, 1, kb + 128);
    BAR(); mfma16(0, Ra, B0); BAR();
    // ph6: (m4-7, ks0)
    rdA(Ra, 1, 1, 0); rdB(B1, 1, 1); stB(1, 0, kb + 192);
    BAR(); mfma16(1, Rb, B0); BAR();
    // ph7: (m0-3, ks1)
    rdA(Rb, 1, 1, 1); stA(1, 0, kb + 192);
    BAR(); mfma16(0, Ra, B1); BAR();
    // ph8: (m4-7, ks1); counted wait -> t2 complete; read buf0 (= t2) AFTER barrier
    stB(1, 1, kb + 192); WAIT_VM(6);
    BAR();
    rdA(Ra, 0, 0, 0); rdB(B0, 0, 0);
    mfma16(1, Rb, B1); BAR();
  }

  // epilogue: tiles 62 (buf0) and 63 (buf1); only remaining stage is t63.Aks1
  rdA(Rb, 0, 0, 1); stA(1, 1, 4032);
  BAR(); mfma16(0, Ra, B0); BAR();
  rdA(Ra, 0, 1, 0); rdB(B1, 0, 1);
  BAR(); mfma16(1, Rb, B0); BAR();
  rdA(Rb, 0, 1, 1);
  BAR(); mfma16(0, Ra, B1); BAR();
  WAIT_VM(0);  // drain: t63 fully landed
  BAR();
  rdA(Ra, 1, 0, 0); rdB(B0, 1, 0);
  mfma16(1, Rb, B1); BAR();
  rdA(Rb, 1, 0, 1);
  mfma16(0, Ra, B0);
  rdA(Ra, 1, 1, 0); rdB(B1, 1, 1);
  mfma16(1, Rb, B0);
  rdA(Rb, 1, 1, 1);
  mfma16(0, Ra, B1);
  mfma16(1, Rb, B1);

  // D: row = quad*4+rr (M dim), col = t16 (N dim)
  #pragma unroll
  for (int i = 0; i < 8; ++i) {
    const int row0 = rowBase + wm128 + i * 16 + quad * 4;
    #pragma unroll
    for (int j = 0; j < 4; ++j) {
      const int col = colBase + wn64 + j * 16 + t16;
      #pragma unroll
      for (int rr = 0; rr < 4; ++rr)
        C[(size_t)(row0 + rr) * 4096 + col] = (bf16)acc[i][j][rr];
    }
  }
}

// ---- mix: out[b][n][o] = sum_{kk<192} Acat[n][kk] * Wcat[o][kk] + bias[o]
//      Acat chunks: kk 0..63 from x (fp32, cvt), 64..127 from XG1, 128..191 from XG2
__global__ __launch_bounds__(256) void mix_k(const float* __restrict__ x, const bf16* __restrict__ XG1,
                                             const bf16* __restrict__ XG2, const bf16* __restrict__ Wc,
                                             const float* __restrict__ bias, float* __restrict__ out) {
  __shared__ bf16 sW[64 * 200];  // stride 200: 16B-aligned rows, 2-way-max bank aliasing (free)
  const int tid = threadIdx.x;
  const int nt = blockIdx.x, b = blockIdx.y;
  {
    // row = tid>>2 (64 rows), quarter = tid&3 covers 48 elems = 6 x bf16x8
    const int rw = tid >> 2, part = tid & 3;
    #pragma unroll
    for (int v = 0; v < 6; ++v)
      *(bf16x8*)(sW + rw * 200 + part * 48 + v * 8) = *(const bf16x8*)(Wc + rw * 192 + part * 48 + v * 8);
  }
  __syncthreads();

  const int lane = tid & 63, wv = tid >> 6;
  const int t16 = lane & 15, quad = lane >> 4;
  const int nBase = nt * 128 + wv * 32;

  f32x4 acc[2][4];
  #pragma unroll
  for (int i = 0; i < 2; ++i)
    #pragma unroll
    for (int j = 0; j < 4; ++j) acc[i][j] = (f32x4){0.f, 0.f, 0.f, 0.f};

  #pragma unroll
  for (int ch = 0; ch < 6; ++ch) {
    bf16x8 a[2];
    #pragma unroll
    for (int i = 0; i < 2; ++i) {
      const int row = nBase + i * 16 + t16;
      if (ch < 2) {
        const float* p = x + (b * 4096 + row) * 64 + ch * 32 + quad * 8;
        float4 f0 = *(const float4*)p;
        float4 f1 = *(const float4*)(p + 4);
        bf16x8 t;
        t[0] = (bf16)f0.x; t[1] = (bf16)f0.y; t[2] = (bf16)f0.z; t[3] = (bf16)f0.w;
        t[4] = (bf16)f1.x; t[5] = (bf16)f1.y; t[6] = (bf16)f1.z; t[7] = (bf16)f1.w;
        a[i] = t;
      } else {
        const bf16* src = (ch < 4) ? XG1 : XG2;
        a[i] = *(const bf16x8*)(src + row * 4096 + b * 64 + (ch & 1) * 32 + quad * 8);
      }
    }
    #pragma unroll
    for (int j = 0; j < 4; ++j) {
      bf16x8 wf = *(const bf16x8*)(sW + (j * 16 + t16) * 200 + ch * 32 + quad * 8);
      #pragma unroll
      for (int i = 0; i < 2; ++i)
        acc[i][j] = __builtin_amdgcn_mfma_f32_16x16x32_bf16(a[i], wf, acc[i][j], 0, 0, 0);
    }
  }

  #pragma unroll
  for (int j = 0; j < 4; ++j) {
    const float bb = bias[j * 16 + t16];
    #pragma unroll
    for (int i = 0; i < 2; ++i) {
      const int n0 = nBase + i * 16 + quad * 4;
      #pragma unroll
      for (int rr = 0; rr < 4; ++rr)
        out[(b * 4096 + n0 + rr) * 64 + j * 16 + t16] = acc[i][j][rr] + bb;
    }
  }
}

extern "C" void kernel_launch(void* const* d_in, const int* in_sizes, int n_in,
                              void* d_out, int out_size, void* d_ws, size_t ws_size,
                              hipStream_t stream) {
  const float* x    = (const float*)d_in[0];  // [64,4096,64]
  const float* adj  = (const float*)d_in[1];  // [4096,16]
  const float* emb  = (const float*)d_in[2];  // [16,4096]
  const float* w    = (const float*)d_in[3];  // [3,64,64]
  const float* bias = (const float*)d_in[4];  // [64]
  float* out = (float*)d_out;

  char* ws = (char*)d_ws;
  const size_t SZ = (size_t)4096 * 4096 * sizeof(bf16);  // 32 MiB
  bf16* S    = (bf16*)(ws);            // [n][m]
  bf16* XG1  = (bf16*)(ws + SZ);       // [n][bc]
  bf16* XG2  = (bf16*)(ws + 2 * SZ);   // [n][bc]
  bf16* XBUF = (bf16*)(ws + 3 * SZ);   // Xt [bc][m], later XG1t [bc][m]
  bf16* Wc   = (bf16*)(ws + 4 * SZ);   // [64][192]

  build_wcat_k<<<48, 256, 0, stream>>>(w, Wc);
  supports_k<<<512, 256, 0, stream>>>(adj, emb, S);
  xpose_x_k<<<dim3(64, 64), 256, 0, stream>>>(x, XBUF);
  gemm256_k<<<256, 512, 0, stream>>>(S, XBUF, XG1);        // XG1 = S @ x
  transpose_bf16_k<<<4096, 256, 0, stream>>>(XG1, XBUF);   // XG1t
  gemm256_k<<<256, 512, 0, stream>>>(S, XBUF, XG2);        // XG2 = S @ XG1
  mix_k<<<dim3(32, 64), 256, 0, stream>>>(x, XG1, XG2, Wc, bias, out);
}

// Round 2
// 444.955 us; speedup vs baseline: 1.0645x; 1.0204x over previous
//
#include <hip/hip_runtime.h>

// AVWGCN: out[b,n,o] = sum_k sum_i xg_k[b,n,i] * w[k,i,o] + bias[o]
//   xg0 = x, xg1 = S@x, xg2 = 2*S@(S@x) - x   (S = softmax(relu(adj@emb), rows))
// Algebra: never form T2; fold "2*" and "-x" into Wcat = [w0-w2 | w1 | 2*w2].
// GEMM: 256x256 8-phase counted-vmcnt template (T3+T4+T5+T1), BK=64, 8 waves,
// 128 KiB LDS double-buffer. LDS k-split [ks][256][32] (64B rows) with chunk-XOR
// swizzle: logical 16B chunk c of row r lives at phys chunk c^((r>>1)&3). Staged
// via permuted GLOBAL source (LDS dst stays lane-linear, m104 rule); reader XORs
// the same key -> each 8-lane b128 group hits all 8 slots of its 128B line
// (round-1 counter: 1.26e7 conflicts with linear chunks = 4-way; this kills it).
// vmcnt never drains to 0 in the main loop (phases 4/8: vmcnt(6)).

typedef __bf16 bf16;
typedef __bf16 bf16x8 __attribute__((ext_vector_type(8)));
typedef float f32x4 __attribute__((ext_vector_type(4)));

__device__ __forceinline__ void async_lds16(const void* g, void* l) {
  __builtin_amdgcn_global_load_lds((const __attribute__((address_space(1))) void*)g,
                                   (__attribute__((address_space(3))) void*)l, 16, 0, 0);
}

#define FENCE() asm volatile("" ::: "memory")
#define BAR()                          \
  do {                                 \
    FENCE();                           \
    __builtin_amdgcn_s_barrier();      \
    FENCE();                           \
  } while (0)
#define WAIT_VM(n) asm volatile("s_waitcnt vmcnt(" #n ")" ::: "memory")

// ---- Wcat[o][kk] bf16, kk in [0,192): [w0-w2 | w1 | 2*w2] transposed to o-rows ----
__global__ __launch_bounds__(256) void build_wcat_k(const float* __restrict__ w, bf16* __restrict__ Wc) {
  int idx = blockIdx.x * 256 + threadIdx.x;
  if (idx >= 64 * 192) return;
  int o = idx / 192, kk = idx - o * 192;
  int k = kk >> 6, i = kk & 63;
  float v;
  if (k == 0)      v = w[i * 64 + o] - w[2 * 4096 + i * 64 + o];
  else if (k == 1) v = w[4096 + i * 64 + o];
  else             v = 2.f * w[2 * 4096 + i * 64 + o];
  Wc[idx] = (bf16)v;
}

// ---- S[n][m] = softmax(relu(adj@emb)) rows, stored bf16. 8 rows per block. ----
__global__ __launch_bounds__(256) void supports_k(const float* __restrict__ adj,
                                                  const float* __restrict__ emb,
                                                  bf16* __restrict__ S) {
  __shared__ float sadj[8][16];
  __shared__ float sred[4];
  const int tid = threadIdx.x;
  const int n0 = blockIdx.x * 8;
  if (tid < 128) sadj[tid >> 4][tid & 15] = adj[n0 * 16 + tid];
  __syncthreads();
  for (int r = 0; r < 8; ++r) {
    float vals[16];
    float mx = 0.f;  // relu => max >= 0
    #pragma unroll
    for (int it = 0; it < 16; ++it) {
      const int j = it * 256 + tid;
      float v = 0.f;
      #pragma unroll
      for (int e = 0; e < 16; ++e) v = fmaf(sadj[r][e], emb[e * 4096 + j], v);
      v = fmaxf(v, 0.f);
      vals[it] = v;
      mx = fmaxf(mx, v);
    }
    #pragma unroll
    for (int off = 32; off > 0; off >>= 1) mx = fmaxf(mx, __shfl_xor(mx, off, 64));
    if ((tid & 63) == 0) sred[tid >> 6] = mx;
    __syncthreads();
    mx = fmaxf(fmaxf(sred[0], sred[1]), fmaxf(sred[2], sred[3]));
    float sum = 0.f;
    #pragma unroll
    for (int it = 0; it < 16; ++it) {
      float ev = __expf(vals[it] - mx);
      vals[it] = ev;
      sum += ev;
    }
    #pragma unroll
    for (int off = 32; off > 0; off >>= 1) sum += __shfl_xor(sum, off, 64);
    __syncthreads();  // all reads of sred (max) done before reuse
    if ((tid & 63) == 0) sred[tid >> 6] = sum;
    __syncthreads();
    const float inv = 1.f / (sred[0] + sred[1] + sred[2] + sred[3]);
    bf16* Srow = S + (n0 + r) * 4096;
    #pragma unroll
    for (int it = 0; it < 16; ++it) Srow[it * 256 + tid] = (bf16)(vals[it] * inv);
    __syncthreads();  // sred reused next r
  }
}

// ---- Xt[b*64+c][m] = bf16(x[b][m][c])  (64x64 fp32 tile via LDS) ----
__global__ __launch_bounds__(256) void xpose_x_k(const float* __restrict__ x, bf16* __restrict__ Xt) {
  __shared__ float tile[64][65];
  const int tid = threadIdx.x;
  const int mt = blockIdx.x, b = blockIdx.y;
  const float* src = x + (b * 4096 + mt * 64) * 64;
  #pragma unroll
  for (int it = 0; it < 16; ++it) {
    const int idx = it * 256 + tid;
    tile[idx >> 6][idx & 63] = src[idx];  // idx = m_local*64 + c, coalesced
  }
  __syncthreads();
  #pragma unroll
  for (int it = 0; it < 16; ++it) {
    const int idx = it * 256 + tid;
    const int rr = idx >> 6, cc = idx & 63;  // rr = c (out row), cc = m_local (out col)
    Xt[(b * 64 + rr) * 4096 + mt * 64 + cc] = (bf16)tile[cc][rr];
  }
}

// ---- bf16 4096x4096 transpose: outT[j][i] = in[i][j] ----
__global__ __launch_bounds__(256) void transpose_bf16_k(const bf16* __restrict__ in, bf16* __restrict__ outT) {
  __shared__ bf16 tile[64][65];
  const int tid = threadIdx.x;
  const int ti = blockIdx.x & 63, tj = blockIdx.x >> 6;
  #pragma unroll
  for (int it = 0; it < 16; ++it) {
    const int idx = it * 256 + tid;
    tile[idx >> 6][idx & 63] = in[(ti * 64 + (idx >> 6)) * 4096 + tj * 64 + (idx & 63)];
  }
  __syncthreads();
  #pragma unroll
  for (int it = 0; it < 16; ++it) {
    const int idx = it * 256 + tid;
    const int rr = idx >> 6, cc = idx & 63;
    outT[(tj * 64 + rr) * 4096 + ti * 64 + cc] = tile[cc][rr];
  }
}

// ---- C[n][bc] = A[n][:] . Bt[bc][:]  (4096^3, both operands K-contig row-major) ----
// 256x256 tile, BK=64, 512 threads = 8 waves (2M x 4N), per-wave 128x64 output,
// acc[8][4] f32x4. 8-phase schedule over 2 K-tiles (buf0 = even tile, buf1 = odd):
//   ph p: { ds_read frags for p+1 | stage 1 half-tile (2 x global_load_lds 16B) |
//           s_barrier | setprio(1) 16xMFMA setprio(0) | s_barrier }
// vmcnt(6) only at ph4/ph8 (3 half-tiles = 6 loads stay in flight). Stage order
// per iter: ph1 t1.Aks1 | ph2 t2.Bks0 | ph3 t2.Aks0 | ph4 t2.Bks1 | ph5 t2.Aks1 |
// ph6 t3.Bks0 | ph7 t3.Aks0 | ph8 t3.Bks1 — each region's reads are issued >=2
// phases before its re-stage, and ph4/ph8 read the fresh buffer AFTER the
// post-vmcnt barrier (cross-wave landing guarantee).
// Chunk swizzle: phys16Bchunk(row, c) = c ^ ((row>>1)&3); applied on the global
// source in staging (dst lane-linear) and on the ds_read chunk offset.
__global__ __launch_bounds__(512, 2) void gemm256_k(const bf16* __restrict__ A,
                                                    const bf16* __restrict__ Bt,
                                                    bf16* __restrict__ C) {
  __shared__ bf16 As[2][2][256][32];  // [buf][ks][row][k'] : 64 KiB
  __shared__ bf16 Bs[2][2][256][32];  // 64 KiB

  const int tid = threadIdx.x;
  const int bid = blockIdx.x;
  const int wg = (bid & 7) * 32 + (bid >> 3);  // XCD swizzle, 256 % 8 == 0 -> bijective
  const int tm = wg >> 4, tn = wg & 15;
  const int rowBase = tm * 256, colBase = tn * 256;

  const int wv = tid >> 6, lane = tid & 63;
  const int wm = wv >> 2, wn = wv & 3;
  const int t16 = lane & 15, quad = lane >> 4;
  const int wv16 = wv * 16;
  const int q8 = (quad ^ ((t16 >> 1) & 3)) * 8;  // swizzled phys chunk for ds_read
  const int wm128 = wm * 128;
  const int wn64 = wn * 64;

  // staging: thread t -> row t>>2 (128 rows/load); lane writes phys chunk t&3,
  // which holds logical chunk (t&3)^key(row), key = (row>>1)&3 = (t>>3)&3
  const int sr = tid >> 2;
  const int sc = ((tid & 3) ^ ((tid >> 3) & 3)) * 8;
  const bf16* gA = A + (size_t)(rowBase + sr) * 4096 + sc;
  const bf16* gB = Bt + (size_t)(colBase + sr) * 4096 + sc;

  f32x4 acc[8][4];
  #pragma unroll
  for (int i = 0; i < 8; ++i)
    #pragma unroll
    for (int j = 0; j < 4; ++j) acc[i][j] = (f32x4){0.f, 0.f, 0.f, 0.f};

  auto stA = [&](int buf, int s, int k0) {
    async_lds16(gA + k0 + s * 32, &As[buf][s][wv16][0]);
    async_lds16(gA + 524288 + k0 + s * 32, &As[buf][s][128 + wv16][0]);
  };
  auto stB = [&](int buf, int s, int k0) {
    async_lds16(gB + k0 + s * 32, &Bs[buf][s][wv16][0]);
    async_lds16(gB + 524288 + k0 + s * 32, &Bs[buf][s][128 + wv16][0]);
  };

  bf16x8 Ra[4], Rb[4], B0[4], B1[4];
  auto rdA = [&](bf16x8* R, int buf, int s, int g) {
    #pragma unroll
    for (int i = 0; i < 4; ++i)
      R[i] = *(const bf16x8*)&As[buf][s][wm128 + (g * 4 + i) * 16 + t16][q8];
  };
  auto rdB = [&](bf16x8* R, int buf, int s) {
    #pragma unroll
    for (int j = 0; j < 4; ++j)
      R[j] = *(const bf16x8*)&Bs[buf][s][wn64 + j * 16 + t16][q8];
  };
  auto mfma16 = [&](int g, const bf16x8* R, const bf16x8* Bv) {
    __builtin_amdgcn_s_setprio(1);
    #pragma unroll
    for (int i = 0; i < 4; ++i)
      #pragma unroll
      for (int j = 0; j < 4; ++j)
        acc[g * 4 + i][j] =
            __builtin_amdgcn_mfma_f32_16x16x32_bf16(R[i], Bv[j], acc[g * 4 + i][j], 0, 0, 0);
    __builtin_amdgcn_s_setprio(0);
  };

  // prologue: t0 -> buf0 (4 halves, 8 loads), t1 -> buf1 (3 halves, 6 loads)
  stB(0, 0, 0); stA(0, 0, 0); stB(0, 1, 0); stA(0, 1, 0);
  stB(1, 0, 64); stA(1, 0, 64); stB(1, 1, 64);
  WAIT_VM(6);  // t0 fully landed; t1's 3 halves may remain in flight
  BAR();
  rdA(Ra, 0, 0, 0);
  rdB(B0, 0, 0);

  for (int it = 0; it < 31; ++it) {
    const int kb = it * 128;
    // ph1: compute t0 (m0-3, ks0)
    rdA(Rb, 0, 0, 1); stA(1, 1, kb + 64);
    BAR(); mfma16(0, Ra, B0); BAR();
    // ph2: (m4-7, ks0)
    rdA(Ra, 0, 1, 0); rdB(B1, 0, 1); stB(0, 0, kb + 128);
    BAR(); mfma16(1, Rb, B0); BAR();
    // ph3: (m0-3, ks1)
    rdA(Rb, 0, 1, 1); stA(0, 0, kb + 128);
    BAR(); mfma16(0, Ra, B1); BAR();
    // ph4: (m4-7, ks1); counted wait -> t1 complete; read buf1 AFTER barrier
    stB(0, 1, kb + 128); WAIT_VM(6);
    BAR();
    rdA(Ra, 1, 0, 0); rdB(B0, 1, 0);
    mfma16(1, Rb, B1); BAR();
    // ph5: compute t1 (m0-3, ks0)
    rdA(Rb, 1, 0, 1); stA(0, 1, kb + 128);
    BAR(); mfma16(0, Ra, B0); BAR();
    // ph6: (m4-7, ks0)
    rdA(Ra, 1, 1, 0); rdB(B1, 1, 1); stB(1, 0, kb + 192);
    BAR(); mfma16(1, Rb, B0); BAR();
    // ph7: (m0-3, ks1)
    rdA(Rb, 1, 1, 1); stA(1, 0, kb + 192);
    BAR(); mfma16(0, Ra, B1); BAR();
    // ph8: (m4-7, ks1); counted wait -> t2 complete; read buf0 (= t2) AFTER barrier
    stB(1, 1, kb + 192); WAIT_VM(6);
    BAR();
    rdA(Ra, 0, 0, 0); rdB(B0, 0, 0);
    mfma16(1, Rb, B1); BAR();
  }

  // epilogue: tiles 62 (buf0) and 63 (buf1); only remaining stage is t63.Aks1
  rdA(Rb, 0, 0, 1); stA(1, 1, 4032);
  BAR(); mfma16(0, Ra, B0); BAR();
  rdA(Ra, 0, 1, 0); rdB(B1, 0, 1);
  BAR(); mfma16(1, Rb, B0); BAR();
  rdA(Rb, 0, 1, 1);
  BAR(); mfma16(0, Ra, B1); BAR();
  WAIT_VM(0);  // drain: t63 fully landed
  BAR();
  rdA(Ra, 1, 0, 0); rdB(B0, 1, 0);
  mfma16(1, Rb, B1); BAR();
  rdA(Rb, 1, 0, 1);
  mfma16(0, Ra, B0);
  rdA(Ra, 1, 1, 0); rdB(B1, 1, 1);
  mfma16(1, Rb, B0);
  rdA(Rb, 1, 1, 1);
  mfma16(0, Ra, B1);
  mfma16(1, Rb, B1);

  // D: row = quad*4+rr (M dim), col = t16 (N dim)
  #pragma unroll
  for (int i = 0; i < 8; ++i) {
    const int row0 = rowBase + wm128 + i * 16 + quad * 4;
    #pragma unroll
    for (int j = 0; j < 4; ++j) {
      const int col = colBase + wn64 + j * 16 + t16;
      #pragma unroll
      for (int rr = 0; rr < 4; ++rr)
        C[(size_t)(row0 + rr) * 4096 + col] = (bf16)acc[i][j][rr];
    }
  }
}

// ---- mix: out[b][n][o] = sum_{kk<192} Acat[n][kk] * Wcat[o][kk] + bias[o]
//      Acat chunks: kk 0..63 from x (fp32, cvt), 64..127 from XG1, 128..191 from XG2
__global__ __launch_bounds__(256) void mix_k(const float* __restrict__ x, const bf16* __restrict__ XG1,
                                             const bf16* __restrict__ XG2, const bf16* __restrict__ Wc,
                                             const float* __restrict__ bias, float* __restrict__ out) {
  __shared__ bf16 sW[64 * 200];  // stride 200: 16B-aligned rows, 2-way-max bank aliasing (free)
  const int tid = threadIdx.x;
  const int nt = blockIdx.x, b = blockIdx.y;
  {
    // row = tid>>2 (64 rows), quarter = tid&3 covers 48 elems = 6 x bf16x8
    const int rw = tid >> 2, part = tid & 3;
    #pragma unroll
    for (int v = 0; v < 6; ++v)
      *(bf16x8*)(sW + rw * 200 + part * 48 + v * 8) = *(const bf16x8*)(Wc + rw * 192 + part * 48 + v * 8);
  }
  __syncthreads();

  const int lane = tid & 63, wv = tid >> 6;
  const int t16 = lane & 15, quad = lane >> 4;
  const int nBase = nt * 128 + wv * 32;

  f32x4 acc[2][4];
  #pragma unroll
  for (int i = 0; i < 2; ++i)
    #pragma unroll
    for (int j = 0; j < 4; ++j) acc[i][j] = (f32x4){0.f, 0.f, 0.f, 0.f};

  #pragma unroll
  for (int ch = 0; ch < 6; ++ch) {
    bf16x8 a[2];
    #pragma unroll
    for (int i = 0; i < 2; ++i) {
      const int row = nBase + i * 16 + t16;
      if (ch < 2) {
        const float* p = x + (b * 4096 + row) * 64 + ch * 32 + quad * 8;
        float4 f0 = *(const float4*)p;
        float4 f1 = *(const float4*)(p + 4);
        bf16x8 t;
        t[0] = (bf16)f0.x; t[1] = (bf16)f0.y; t[2] = (bf16)f0.z; t[3] = (bf16)f0.w;
        t[4] = (bf16)f1.x; t[5] = (bf16)f1.y; t[6] = (bf16)f1.z; t[7] = (bf16)f1.w;
        a[i] = t;
      } else {
        const bf16* src = (ch < 4) ? XG1 : XG2;
        a[i] = *(const bf16x8*)(src + row * 4096 + b * 64 + (ch & 1) * 32 + quad * 8);
      }
    }
    #pragma unroll
    for (int j = 0; j < 4; ++j) {
      bf16x8 wf = *(const bf16x8*)(sW + (j * 16 + t16) * 200 + ch * 32 + quad * 8);
      #pragma unroll
      for (int i = 0; i < 2; ++i)
        acc[i][j] = __builtin_amdgcn_mfma_f32_16x16x32_bf16(a[i], wf, acc[i][j], 0, 0, 0);
    }
  }

  #pragma unroll
  for (int j = 0; j < 4; ++j) {
    const float bb = bias[j * 16 + t16];
    #pragma unroll
    for (int i = 0; i < 2; ++i) {
      const int n0 = nBase + i * 16 + quad * 4;
      #pragma unroll
      for (int rr = 0; rr < 4; ++rr)
        out[(b * 4096 + n0 + rr) * 64 + j * 16 + t16] = acc[i][j][rr] + bb;
    }
  }
}

extern "C" void kernel_launch(void* const* d_in, const int* in_sizes, int n_in,
                              void* d_out, int out_size, void* d_ws, size_t ws_size,
                              hipStream_t stream) {
  const float* x    = (const float*)d_in[0];  // [64,4096,64]
  const float* adj  = (const float*)d_in[1];  // [4096,16]
  const float* emb  = (const float*)d_in[2];  // [16,4096]
  const float* w    = (const float*)d_in[3];  // [3,64,64]
  const float* bias = (const float*)d_in[4];  // [64]
  float* out = (float*)d_out;

  char* ws = (char*)d_ws;
  const size_t SZ = (size_t)4096 * 4096 * sizeof(bf16);  // 32 MiB
  bf16* S    = (bf16*)(ws);            // [n][m]
  bf16* XG1  = (bf16*)(ws + SZ);       // [n][bc]
  bf16* XG2  = (bf16*)(ws + 2 * SZ);   // [n][bc]
  bf16* XBUF = (bf16*)(ws + 3 * SZ);   // Xt [bc][m], later XG1t [bc][m]
  bf16* Wc   = (bf16*)(ws + 4 * SZ);   // [64][192]

  build_wcat_k<<<48, 256, 0, stream>>>(w, Wc);
  supports_k<<<512, 256, 0, stream>>>(adj, emb, S);
  xpose_x_k<<<dim3(64, 64), 256, 0, stream>>>(x, XBUF);
  gemm256_k<<<256, 512, 0, stream>>>(S, XBUF, XG1);        // XG1 = S @ x
  transpose_bf16_k<<<4096, 256, 0, stream>>>(XG1, XBUF);   // XG1t
  gemm256_k<<<256, 512, 0, stream>>>(S, XBUF, XG2);        // XG2 = S @ XG1
  mix_k<<<dim3(32, 64), 256, 0, stream>>>(x, XG1, XG2, Wc, bias, out);
}

// Round 3
// 434.130 us; speedup vs baseline: 1.0910x; 1.0249x over previous
//
#include <hip/hip_runtime.h>

// AVWGCN: out[b,n,o] = sum_k sum_i xg_k[b,n,i] * w[k,i,o] + bias[o]
//   xg0 = x, xg1 = S@x, xg2 = 2*S@(S@x) - x   (S = softmax(relu(adj@emb), rows))
// Algebra: never form T2; fold "2*" and "-x" into Wcat = [w0-w2 | w1 | 2*w2].
// GEMM: 256x256, BK=64, 8 waves, 128 KiB LDS dbuf, chunk-XOR swizzle (0 conflicts,
// round-2 verified). SINGLE barrier per region (8/2 K-tiles, was 16): legal because
// regs are double-buffered (region-p reads feed region-p+1 MFMAs), so every stage
// site has its old data's consuming MFMA in region <= p-1 -> lgkmcnt forces read
// completion before that wave passes bar_{p-1}, and the stage issues after it.
// MFMAs are NOT barrier-boxed -> waves drift ~1 region and cover each other's
// read/stage windows. vmcnt counted (6) only at R4/R8; never 0 in main loop.

typedef __bf16 bf16;
typedef __bf16 bf16x8 __attribute__((ext_vector_type(8)));
typedef float f32x4 __attribute__((ext_vector_type(4)));

__device__ __forceinline__ void async_lds16(const void* g, void* l) {
  __builtin_amdgcn_global_load_lds((const __attribute__((address_space(1))) void*)g,
                                   (__attribute__((address_space(3))) void*)l, 16, 0, 0);
}

#define FENCE() asm volatile("" ::: "memory")
#define BAR()                          \
  do {                                 \
    FENCE();                           \
    __builtin_amdgcn_s_barrier();      \
    FENCE();                           \
  } while (0)
#define WAIT_VM(n) asm volatile("s_waitcnt vmcnt(" #n ")" ::: "memory")

// ---- Wcat[o][kk] bf16, kk in [0,192): [w0-w2 | w1 | 2*w2] transposed to o-rows ----
__global__ __launch_bounds__(256) void build_wcat_k(const float* __restrict__ w, bf16* __restrict__ Wc) {
  int idx = blockIdx.x * 256 + threadIdx.x;
  if (idx >= 64 * 192) return;
  int o = idx / 192, kk = idx - o * 192;
  int k = kk >> 6, i = kk & 63;
  float v;
  if (k == 0)      v = w[i * 64 + o] - w[2 * 4096 + i * 64 + o];
  else if (k == 1) v = w[4096 + i * 64 + o];
  else             v = 2.f * w[2 * 4096 + i * 64 + o];
  Wc[idx] = (bf16)v;
}

// ---- S[n][m] = softmax(relu(adj@emb)) rows, stored bf16. 8 rows per block. ----
__global__ __launch_bounds__(256) void supports_k(const float* __restrict__ adj,
                                                  const float* __restrict__ emb,
                                                  bf16* __restrict__ S) {
  __shared__ float sadj[8][16];
  __shared__ float sred[4];
  const int tid = threadIdx.x;
  const int n0 = blockIdx.x * 8;
  if (tid < 128) sadj[tid >> 4][tid & 15] = adj[n0 * 16 + tid];
  __syncthreads();
  for (int r = 0; r < 8; ++r) {
    float vals[16];
    float mx = 0.f;  // relu => max >= 0
    #pragma unroll
    for (int it = 0; it < 16; ++it) {
      const int j = it * 256 + tid;
      float v = 0.f;
      #pragma unroll
      for (int e = 0; e < 16; ++e) v = fmaf(sadj[r][e], emb[e * 4096 + j], v);
      v = fmaxf(v, 0.f);
      vals[it] = v;
      mx = fmaxf(mx, v);
    }
    #pragma unroll
    for (int off = 32; off > 0; off >>= 1) mx = fmaxf(mx, __shfl_xor(mx, off, 64));
    if ((tid & 63) == 0) sred[tid >> 6] = mx;
    __syncthreads();
    mx = fmaxf(fmaxf(sred[0], sred[1]), fmaxf(sred[2], sred[3]));
    float sum = 0.f;
    #pragma unroll
    for (int it = 0; it < 16; ++it) {
      float ev = __expf(vals[it] - mx);
      vals[it] = ev;
      sum += ev;
    }
    #pragma unroll
    for (int off = 32; off > 0; off >>= 1) sum += __shfl_xor(sum, off, 64);
    __syncthreads();  // all reads of sred (max) done before reuse
    if ((tid & 63) == 0) sred[tid >> 6] = sum;
    __syncthreads();
    const float inv = 1.f / (sred[0] + sred[1] + sred[2] + sred[3]);
    bf16* Srow = S + (n0 + r) * 4096;
    #pragma unroll
    for (int it = 0; it < 16; ++it) Srow[it * 256 + tid] = (bf16)(vals[it] * inv);
    __syncthreads();  // sred reused next r
  }
}

// ---- Xt[b*64+c][m] = bf16(x[b][m][c])  (64x64 fp32 tile via LDS) ----
__global__ __launch_bounds__(256) void xpose_x_k(const float* __restrict__ x, bf16* __restrict__ Xt) {
  __shared__ float tile[64][65];
  const int tid = threadIdx.x;
  const int mt = blockIdx.x, b = blockIdx.y;
  const float* src = x + (b * 4096 + mt * 64) * 64;
  #pragma unroll
  for (int it = 0; it < 16; ++it) {
    const int idx = it * 256 + tid;
    tile[idx >> 6][idx & 63] = src[idx];  // idx = m_local*64 + c, coalesced
  }
  __syncthreads();
  #pragma unroll
  for (int it = 0; it < 16; ++it) {
    const int idx = it * 256 + tid;
    const int rr = idx >> 6, cc = idx & 63;  // rr = c (out row), cc = m_local (out col)
    Xt[(b * 64 + rr) * 4096 + mt * 64 + cc] = (bf16)tile[cc][rr];
  }
}

// ---- bf16 4096x4096 transpose: outT[j][i] = in[i][j]  (fallback if ws too small) ----
__global__ __launch_bounds__(256) void transpose_bf16_k(const bf16* __restrict__ in, bf16* __restrict__ outT) {
  __shared__ bf16 tile[64][65];
  const int tid = threadIdx.x;
  const int ti = blockIdx.x & 63, tj = blockIdx.x >> 6;
  #pragma unroll
  for (int it = 0; it < 16; ++it) {
    const int idx = it * 256 + tid;
    tile[idx >> 6][idx & 63] = in[(ti * 64 + (idx >> 6)) * 4096 + tj * 64 + (idx & 63)];
  }
  __syncthreads();
  #pragma unroll
  for (int it = 0; it < 16; ++it) {
    const int idx = it * 256 + tid;
    const int rr = idx >> 6, cc = idx & 63;
    outT[(tj * 64 + rr) * 4096 + ti * 64 + cc] = tile[cc][rr];
  }
}

// ---- C[n][bc] = A[n][:] . Bt[bc][:]  (4096^3, both operands K-contig row-major) ----
// Regions R1..R8 over 2 K-tiles, ONE barrier each. Region p: { ds_read frags for
// region p+1 (R1/R5 also read own operands post-buf-switch) | stage 1 half-tile |
// 16 MFMA | [R4/R8: WAIT_VM(6)] | BAR }. Stage order per iter: R1 t_{2i+1}.Aks1 |
// R2 t_{2i+2}.Bks0 | R3 .Aks0 | R4 .Bks1 | R5 .Aks1 | R6 t_{2i+3}.Bks0 | R7 .Aks0
// | R8 .Bks1. Every stage site: old data's consuming MFMA is in region <= p-1.
// Chunk swizzle: phys16Bchunk(row,c) = c ^ ((row>>1)&3), applied on global source
// (LDS dst lane-linear) and on ds_read chunk offset (0 conflicts, round-2 PMC).
// Optional Ct: transposed C store (for XG1t), 8B/lane; L2 merges (block covers
// full lines of Ct rows colBase..colBase+255).
__global__ __launch_bounds__(512, 2) void gemm256_k(const bf16* __restrict__ A,
                                                    const bf16* __restrict__ Bt,
                                                    bf16* __restrict__ C,
                                                    bf16* __restrict__ Ct) {
  __shared__ bf16 As[2][2][256][32];  // [buf][ks][row][k'] : 64 KiB
  __shared__ bf16 Bs[2][2][256][32];  // 64 KiB

  const int tid = threadIdx.x;
  const int bid = blockIdx.x;
  const int wg = (bid & 7) * 32 + (bid >> 3);  // XCD swizzle, 256 % 8 == 0 -> bijective
  const int tm = wg >> 4, tn = wg & 15;
  const int rowBase = tm * 256, colBase = tn * 256;

  const int wv = tid >> 6, lane = tid & 63;
  const int wm = wv >> 2, wn = wv & 3;
  const int t16 = lane & 15, quad = lane >> 4;
  const int wv16 = wv * 16;
  const int q8 = (quad ^ ((t16 >> 1) & 3)) * 8;  // swizzled phys chunk for ds_read
  const int wm128 = wm * 128;
  const int wn64 = wn * 64;

  // staging: thread t -> row t>>2 (128 rows/load); lane writes phys chunk t&3,
  // which holds logical chunk (t&3)^key(row), key = (row>>1)&3 = (t>>3)&3
  const int sr = tid >> 2;
  const int sc = ((tid & 3) ^ ((tid >> 3) & 3)) * 8;
  const bf16* gA = A + (size_t)(rowBase + sr) * 4096 + sc;
  const bf16* gB = Bt + (size_t)(colBase + sr) * 4096 + sc;

  f32x4 acc[8][4];
  #pragma unroll
  for (int i = 0; i < 8; ++i)
    #pragma unroll
    for (int j = 0; j < 4; ++j) acc[i][j] = (f32x4){0.f, 0.f, 0.f, 0.f};

  auto stA = [&](int buf, int s, int k0) {
    async_lds16(gA + k0 + s * 32, &As[buf][s][wv16][0]);
    async_lds16(gA + 524288 + k0 + s * 32, &As[buf][s][128 + wv16][0]);
  };
  auto stB = [&](int buf, int s, int k0) {
    async_lds16(gB + k0 + s * 32, &Bs[buf][s][wv16][0]);
    async_lds16(gB + 524288 + k0 + s * 32, &Bs[buf][s][128 + wv16][0]);
  };

  bf16x8 Ra[4], Rb[4], B0[4], B1[4];
  auto rdA = [&](bf16x8* R, int buf, int s, int g) {
    #pragma unroll
    for (int i = 0; i < 4; ++i)
      R[i] = *(const bf16x8*)&As[buf][s][wm128 + (g * 4 + i) * 16 + t16][q8];
  };
  auto rdB = [&](bf16x8* R, int buf, int s) {
    #pragma unroll
    for (int j = 0; j < 4; ++j)
      R[j] = *(const bf16x8*)&Bs[buf][s][wn64 + j * 16 + t16][q8];
  };
  auto mfma16 = [&](int g, const bf16x8* R, const bf16x8* Bv) {
    __builtin_amdgcn_s_setprio(1);
    #pragma unroll
    for (int i = 0; i < 4; ++i)
      #pragma unroll
      for (int j = 0; j < 4; ++j)
        acc[g * 4 + i][j] =
            __builtin_amdgcn_mfma_f32_16x16x32_bf16(R[i], Bv[j], acc[g * 4 + i][j], 0, 0, 0);
    __builtin_amdgcn_s_setprio(0);
  };

  // prologue: t0 -> buf0 (4 halves, 8 loads), t1 -> buf1 (3 halves, 6 loads)
  stB(0, 0, 0); stA(0, 0, 0); stB(0, 1, 0); stA(0, 1, 0);
  stB(1, 0, 64); stA(1, 0, 64); stB(1, 1, 64);
  WAIT_VM(6);  // t0 fully landed; t1's 3 halves stay in flight
  BAR();

  for (int it = 0; it < 31; ++it) {
    const int kb = it * 128;
    // R1: buf-switch reads (same-region consume of Ra/B0) + lookahead Rb
    rdA(Ra, 0, 0, 0); rdB(B0, 0, 0); rdA(Rb, 0, 0, 1);
    stA(1, 1, kb + 64);
    mfma16(0, Ra, B0);
    BAR();
    // R2
    rdA(Ra, 0, 1, 0); rdB(B1, 0, 1);
    stB(0, 0, kb + 128);
    mfma16(1, Rb, B0);
    BAR();
    // R3
    rdA(Rb, 0, 1, 1);
    stA(0, 0, kb + 128);
    mfma16(0, Ra, B1);
    BAR();
    // R4: counted wait -> buf1 (t_{2it+1}) fully landed after this barrier
    stB(0, 1, kb + 128);
    mfma16(1, Rb, B1);
    WAIT_VM(6);
    BAR();
    // R5: buf-switch reads of buf1 + lookahead
    rdA(Ra, 1, 0, 0); rdB(B0, 1, 0); rdA(Rb, 1, 0, 1);
    stA(0, 1, kb + 128);
    mfma16(0, Ra, B0);
    BAR();
    // R6
    rdA(Ra, 1, 1, 0); rdB(B1, 1, 1);
    stB(1, 0, kb + 192);
    mfma16(1, Rb, B0);
    BAR();
    // R7
    rdA(Rb, 1, 1, 1);
    stA(1, 0, kb + 192);
    mfma16(0, Ra, B1);
    BAR();
    // R8: counted wait -> buf0 (t_{2it+2}) fully landed after this barrier
    stB(1, 1, kb + 192);
    mfma16(1, Rb, B1);
    WAIT_VM(6);
    BAR();
  }

  // epilogue: tiles 62 (buf0) and 63 (buf1); only remaining stage is t63.Aks1
  rdA(Ra, 0, 0, 0); rdB(B0, 0, 0); rdA(Rb, 0, 0, 1);
  stA(1, 1, 4032);
  mfma16(0, Ra, B0);
  BAR();
  rdA(Ra, 0, 1, 0); rdB(B1, 0, 1);
  mfma16(1, Rb, B0);
  BAR();
  rdA(Rb, 0, 1, 1);
  mfma16(0, Ra, B1);
  BAR();
  mfma16(1, Rb, B1);
  WAIT_VM(0);  // drain: t63 fully landed
  BAR();
  rdA(Ra, 1, 0, 0); rdB(B0, 1, 0); rdA(Rb, 1, 0, 1);
  mfma16(0, Ra, B0);
  rdA(Ra, 1, 1, 0); rdB(B1, 1, 1);
  mfma16(1, Rb, B0);
  rdA(Rb, 1, 1, 1);
  mfma16(0, Ra, B1);
  mfma16(1, Rb, B1);

  // D: row = quad*4+rr (M dim), col = t16 (N dim)
  #pragma unroll
  for (int i = 0; i < 8; ++i) {
    const int row0 = rowBase + wm128 + i * 16 + quad * 4;
    #pragma unroll
    for (int j = 0; j < 4; ++j) {
      const int col = colBase + wn64 + j * 16 + t16;
      #pragma unroll
      for (int rr = 0; rr < 4; ++rr)
        C[(size_t)(row0 + rr) * 4096 + col] = (bf16)acc[i][j][rr];
    }
  }
  if (Ct) {  // transposed store: Ct[col][row], 4 contiguous bf16 (8B) per frag
    #pragma unroll
    for (int i = 0; i < 8; ++i) {
      const int row0 = rowBase + wm128 + i * 16 + quad * 4;
      #pragma unroll
      for (int j = 0; j < 4; ++j) {
        const int col = colBase + wn64 + j * 16 + t16;
        union { bf16 h[4]; uint2 u; } pk;
        #pragma unroll
        for (int rr = 0; rr < 4; ++rr) pk.h[rr] = (bf16)acc[i][j][rr];
        *(uint2*)(Ct + (size_t)col * 4096 + row0) = pk.u;
      }
    }
  }
}

// ---- mix: out[b][n][o] = sum_{kk<192} Acat[n][kk] * Wcat[o][kk] + bias[o]
//      Acat chunks: kk 0..63 from x (fp32, cvt), 64..127 from XG1, 128..191 from XG2
__global__ __launch_bounds__(256) void mix_k(const float* __restrict__ x, const bf16* __restrict__ XG1,
                                             const bf16* __restrict__ XG2, const bf16* __restrict__ Wc,
                                             const float* __restrict__ bias, float* __restrict__ out) {
  __shared__ bf16 sW[64 * 200];  // stride 200: 16B-aligned rows, 2-way-max bank aliasing (free)
  const int tid = threadIdx.x;
  const int nt = blockIdx.x, b = blockIdx.y;
  {
    // row = tid>>2 (64 rows), quarter = tid&3 covers 48 elems = 6 x bf16x8
    const int rw = tid >> 2, part = tid & 3;
    #pragma unroll
    for (int v = 0; v < 6; ++v)
      *(bf16x8*)(sW + rw * 200 + part * 48 + v * 8) = *(const bf16x8*)(Wc + rw * 192 + part * 48 + v * 8);
  }
  __syncthreads();

  const int lane = tid & 63, wv = tid >> 6;
  const int t16 = lane & 15, quad = lane >> 4;
  const int nBase = nt * 128 + wv * 32;

  f32x4 acc[2][4];
  #pragma unroll
  for (int i = 0; i < 2; ++i)
    #pragma unroll
    for (int j = 0; j < 4; ++j) acc[i][j] = (f32x4){0.f, 0.f, 0.f, 0.f};

  #pragma unroll
  for (int ch = 0; ch < 6; ++ch) {
    bf16x8 a[2];
    #pragma unroll
    for (int i = 0; i < 2; ++i) {
      const int row = nBase + i * 16 + t16;
      if (ch < 2) {
        const float* p = x + (b * 4096 + row) * 64 + ch * 32 + quad * 8;
        float4 f0 = *(const float4*)p;
        float4 f1 = *(const float4*)(p + 4);
        bf16x8 t;
        t[0] = (bf16)f0.x; t[1] = (bf16)f0.y; t[2] = (bf16)f0.z; t[3] = (bf16)f0.w;
        t[4] = (bf16)f1.x; t[5] = (bf16)f1.y; t[6] = (bf16)f1.z; t[7] = (bf16)f1.w;
        a[i] = t;
      } else {
        const bf16* src = (ch < 4) ? XG1 : XG2;
        a[i] = *(const bf16x8*)(src + row * 4096 + b * 64 + (ch & 1) * 32 + quad * 8);
      }
    }
    #pragma unroll
    for (int j = 0; j < 4; ++j) {
      bf16x8 wf = *(const bf16x8*)(sW + (j * 16 + t16) * 200 + ch * 32 + quad * 8);
      #pragma unroll
      for (int i = 0; i < 2; ++i)
        acc[i][j] = __builtin_amdgcn_mfma_f32_16x16x32_bf16(a[i], wf, acc[i][j], 0, 0, 0);
    }
  }

  #pragma unroll
  for (int j = 0; j < 4; ++j) {
    const float bb = bias[j * 16 + t16];
    #pragma unroll
    for (int i = 0; i < 2; ++i) {
      const int n0 = nBase + i * 16 + quad * 4;
      #pragma unroll
      for (int rr = 0; rr < 4; ++rr)
        out[(b * 4096 + n0 + rr) * 64 + j * 16 + t16] = acc[i][j][rr] + bb;
    }
  }
}

extern "C" void kernel_launch(void* const* d_in, const int* in_sizes, int n_in,
                              void* d_out, int out_size, void* d_ws, size_t ws_size,
                              hipStream_t stream) {
  const float* x    = (const float*)d_in[0];  // [64,4096,64]
  const float* adj  = (const float*)d_in[1];  // [4096,16]
  const float* emb  = (const float*)d_in[2];  // [16,4096]
  const float* w    = (const float*)d_in[3];  // [3,64,64]
  const float* bias = (const float*)d_in[4];  // [64]
  float* out = (float*)d_out;

  char* ws = (char*)d_ws;
  const size_t SZ = (size_t)4096 * 4096 * sizeof(bf16);  // 32 MiB
  bf16* S    = (bf16*)(ws);            // [n][m]
  bf16* XG1  = (bf16*)(ws + SZ);       // [n][bc]
  bf16* XG2  = (bf16*)(ws + 2 * SZ);   // [n][bc]
  bf16* XBUF = (bf16*)(ws + 3 * SZ);   // Xt [bc][m] (and XG1t fallback)
  const bool fused_t = ws_size >= 5 * SZ + (size_t)(64 * 192 * sizeof(bf16));
  bf16* XG1T = fused_t ? (bf16*)(ws + 4 * SZ) : XBUF;  // [bc][m]
  bf16* Wc   = (bf16*)(ws + (fused_t ? 5 : 4) * SZ);   // [64][192]

  build_wcat_k<<<48, 256, 0, stream>>>(w, Wc);
  supports_k<<<512, 256, 0, stream>>>(adj, emb, S);
  xpose_x_k<<<dim3(64, 64), 256, 0, stream>>>(x, XBUF);
  gemm256_k<<<256, 512, 0, stream>>>(S, XBUF, XG1, fused_t ? XG1T : nullptr);
  if (!fused_t) transpose_bf16_k<<<4096, 256, 0, stream>>>(XG1, XBUF);  // XG1t
  gemm256_k<<<256, 512, 0, stream>>>(S, XG1T, XG2, nullptr);            // XG2 = S @ XG1
  mix_k<<<dim3(32, 64), 256, 0, stream>>>(x, XG1, XG2, Wc, bias, out);
}